// Round 7
// baseline (205.877 us; speedup 1.0000x reference)
//
#include <hip/hip_runtime.h>
#include <cstdint>
#include <cstddef>

// Shapes fixed by the reference harness.
#define MM 2048
#define KK 4096
#define NN 4096
#define GG 32   // K / 128 groups
#define BM 128
#define BN 128
#define BK 64
#define NKT (KK / BK)   // 64 k-tiles

typedef _Float16 half8_t __attribute__((ext_vector_type(8)));
typedef _Float16 half4_t __attribute__((ext_vector_type(4)));
typedef float f32x4 __attribute__((ext_vector_type(4)));

__device__ __forceinline__ void load_lds16(const void* gptr, void* lptr) {
  // 16B-per-lane direct global->LDS (emits global_load_lds_dwordx4).
  // LDS dest = wave-uniform base + lane*16 (NOT a per-lane scatter).
  __builtin_amdgcn_global_load_lds(
      (const __attribute__((address_space(1))) unsigned int*)gptr,
      (__attribute__((address_space(3))) unsigned int*)lptr, 16, 0, 0);
}

// Merged prep: first MM*KK/4 threads convert A fp32->fp16; the rest dequant
// qweight -> fp16 via w = fma(q, s, -z*s). Block-uniform branch.
#define ACNT (MM * KK / 4)
__global__ void prep_kernel(const float* __restrict__ A, const int* __restrict__ q,
                            const float* __restrict__ scales, const float* __restrict__ zeros,
                            _Float16* __restrict__ Ah, _Float16* __restrict__ Wh) {
  const int i = blockIdx.x * blockDim.x + threadIdx.x;
  if (i < ACNT) {
    const float4 v = ((const float4*)A)[i];
    half4_t h;
    h[0] = (_Float16)v.x; h[1] = (_Float16)v.y; h[2] = (_Float16)v.z; h[3] = (_Float16)v.w;
    *(half4_t*)(Ah + 4 * (size_t)i) = h;
  } else {
    const int j = i - ACNT;
    const int e = j << 2;
    const int n = e >> 12;
    const int k = e & (KK - 1);
    const int g = k >> 7;
    const float sc = scales[(n << 5) + g];
    const float zp = zeros[(n << 5) + g];
    const float nzs = -zp * sc;
    const int4 qv = ((const int4*)q)[j];
    half4_t h;
    h[0] = (_Float16)fmaf((float)qv.x, sc, nzs);
    h[1] = (_Float16)fmaf((float)qv.y, sc, nzs);
    h[2] = (_Float16)fmaf((float)qv.z, sc, nzs);
    h[3] = (_Float16)fmaf((float)qv.w, sc, nzs);
    *(half4_t*)(Wh + (size_t)e) = h;
  }
}

// ---------------------------------------------------------------------------
// Pipelined BT-GEMM: 512 threads = 4 compute waves (64x64 each, 4x4 of
// 16x16x32 f16 MFMA) + 4 producer waves (global_load_lds width=16 staging).
// Double-buffered LDS; NO block-wide barrier in the K-loop. Sync via
// monotone LDS counters:
//   ready[b]: producers increment (1 per producer wave) after vmcnt(0) drain
//             of their loads for the tile staged in buffer b.
//   done[b]:  consumers increment after lgkmcnt(0) (frag reads complete).
// Producer stages tile t into b=t&1 when done[b] >= 4*(t/2)  (tile t-2 fully
// consumed). Consumer computes tile t when ready[b] >= 4*((t/2)+1).
// Producer vmcnt(0) drains stall ONLY producer waves; compute waves keep
// issuing MFMA — this is the restructured K-loop the m97 2-barrier shape
// cannot express.
// LDS layout per buffer: row-major [128][64] fp16, 16B-chunk XOR-swizzled
// with (row&7) (2-way aliasing = free; 0 conflicts measured R4-R6).
// ---------------------------------------------------------------------------
__global__ __launch_bounds__(512, 4)
void gemm_pipe(const _Float16* __restrict__ Ah, const _Float16* __restrict__ Wh,
               const float* __restrict__ bias, float* __restrict__ out)
{
  __shared__ __align__(16) _Float16 sA[2][BM * BK];
  __shared__ __align__(16) _Float16 sB[2][BN * BK];
  __shared__ int flg[4];   // [0]=ready b0, [1]=ready b1, [2]=done b0, [3]=done b1

  const int tid = threadIdx.x;
  const int lane = tid & 63;
  const int wave = tid >> 6;    // 0..7

  if (tid == 0) { flg[0] = 0; flg[1] = 0; flg[2] = 0; flg[3] = 0; }
  __syncthreads();              // the only block-wide barrier

  // XCD-aware tile mapping (neutral in R6, zero-cost; kept).
  const int bid = blockIdx.x;
  const int xcd = bid & 7;
  const int slot = bid >> 3;
  const int m0 = (slot >> 2) * BM;
  const int n0 = (xcd * 4 + (slot & 3)) * BN;

  if (wave >= 4) {
    // ---- producer waves ----
    const int pw = wave - 4;            // 0..3
    const int srow = lane >> 3;         // 0..7
    const int scc = lane & 7;           // physical 16B chunk
    const int gchunk = scc ^ srow;      // XOR swizzle (row&7 == srow)
    for (int t = 0; t < NKT; ++t) {
      const int b = t & 1;
      const int k0 = t * BK;
      const int need = 4 * (t >> 1);    // tile t-2 fully consumed
      while (__hip_atomic_load(&flg[2 + b], __ATOMIC_ACQUIRE,
                               __HIP_MEMORY_SCOPE_WORKGROUP) < need)
        __builtin_amdgcn_s_sleep(1);
#pragma unroll
      for (int i = 0; i < 4; ++i) {
        const int c = i * 4 + pw;       // wave-uniform chunk id 0..15
        const int row = c * 8 + srow;
        load_lds16(Ah + (size_t)(m0 + row) * KK + k0 + gchunk * 8, (void*)&sA[b][c * 512]);
        load_lds16(Wh + (size_t)(n0 + row) * KK + k0 + gchunk * 8, (void*)&sB[b][c * 512]);
      }
      __builtin_amdgcn_s_waitcnt(0x0f70);   // vmcnt(0) — this wave's loads only
      if (lane == 0)
        __hip_atomic_fetch_add(&flg[b], 1, __ATOMIC_RELEASE,
                               __HIP_MEMORY_SCOPE_WORKGROUP);
    }
    return;   // producers exit; no barriers below
  }

  // ---- compute waves ----
  const int wr = wave >> 1, wc = wave & 1;
  const int lr = lane & 15, quad = lane >> 4;

  f32x4 acc[4][4];
#pragma unroll
  for (int i = 0; i < 4; ++i)
#pragma unroll
    for (int j = 0; j < 4; ++j) acc[i][j] = (f32x4){0.f, 0.f, 0.f, 0.f};

  for (int t = 0; t < NKT; ++t) {
    const int b = t & 1;
    const int need = 4 * ((t >> 1) + 1);   // tile t fully staged
    while (__hip_atomic_load(&flg[b], __ATOMIC_ACQUIRE,
                             __HIP_MEMORY_SCOPE_WORKGROUP) < need)
      __builtin_amdgcn_s_sleep(1);
#pragma unroll
    for (int ks = 0; ks < 2; ++ks) {
      half8_t a[4], bfr[4];
#pragma unroll
      for (int tt = 0; tt < 4; ++tt) {
        const int rA = wr * 64 + tt * 16 + lr;
        const int j = ks * 4 + quad;
        a[tt] = *(const half8_t*)&sA[b][rA * 64 + ((j ^ (lr & 7)) * 8)];
        const int rB = wc * 64 + tt * 16 + lr;
        bfr[tt] = *(const half8_t*)&sB[b][rB * 64 + ((j ^ (lr & 7)) * 8)];
      }
#pragma unroll
      for (int mi = 0; mi < 4; ++mi)
#pragma unroll
        for (int ni = 0; ni < 4; ++ni)
          acc[mi][ni] = __builtin_amdgcn_mfma_f32_16x16x32_f16(a[mi], bfr[ni], acc[mi][ni], 0, 0, 0);
    }
    __builtin_amdgcn_s_waitcnt(0xc07f);   // lgkmcnt(0) — frag reads complete
    if (lane == 0)
      __hip_atomic_fetch_add(&flg[2 + b], 1, __ATOMIC_RELEASE,
                             __HIP_MEMORY_SCOPE_WORKGROUP);
  }

  // Epilogue. C/D layout: col = lane&15, row = quad*4 + reg.
#pragma unroll
  for (int ni = 0; ni < 4; ++ni) {
    const int n = n0 + wc * 64 + ni * 16 + lr;
    const float bv = bias[n];
#pragma unroll
    for (int mi = 0; mi < 4; ++mi) {
      const int mbase = m0 + wr * 64 + mi * 16 + quad * 4;
#pragma unroll
      for (int r = 0; r < 4; ++r)
        out[(size_t)(mbase + r) * NN + n] = acc[mi][ni][r] + bv;
    }
  }
}

// Fallback (ws too small): fused register-staging GEMM, 256 threads.
__global__ __launch_bounds__(256, 2)
void gemm_fused(const float* __restrict__ Af, const int* __restrict__ qw,
                const float* __restrict__ scales, const float* __restrict__ zeros,
                const float* __restrict__ bias, float* __restrict__ out)
{
  __shared__ __align__(16) _Float16 sA[BM * BK];
  __shared__ __align__(16) _Float16 sB[BN * BK];
  const int tid = threadIdx.x;
  const int lane = tid & 63;
  const int wave = tid >> 6;
  const int wr = wave >> 1, wc = wave & 1;
  const int m0 = (blockIdx.x >> 5) * BM;
  const int n0 = (blockIdx.x & 31) * BN;
  const int lr = lane & 15, quad = lane >> 4;
  f32x4 acc[4][4];
#pragma unroll
  for (int i = 0; i < 4; ++i)
#pragma unroll
    for (int j = 0; j < 4; ++j) acc[i][j] = (f32x4){0.f, 0.f, 0.f, 0.f};
  const int frow = tid >> 4;
  const int fc4 = tid & 15;
  for (int kt = 0; kt < NKT; ++kt) {
    const int k0 = kt * BK;
    const int g = k0 >> 7;
#pragma unroll
    for (int p = 0; p < 8; ++p) {
      const int row = p * 16 + frow;
      const int pc = (fc4 >> 1) ^ (row & 7);
      const int dst = row * 64 + pc * 8 + (fc4 & 1) * 4;
      const float4 avf = *(const float4*)&Af[(size_t)(m0 + row) * KK + k0 + fc4 * 4];
      half4_t ah;
      ah[0] = (_Float16)avf.x; ah[1] = (_Float16)avf.y;
      ah[2] = (_Float16)avf.z; ah[3] = (_Float16)avf.w;
      *(half4_t*)&sA[dst] = ah;
      const int n = n0 + row;
      const float sc = scales[(n << 5) + g];
      const float zp = zeros[(n << 5) + g];
      const float nzs = -zp * sc;
      const int4 qv = *(const int4*)&qw[(size_t)n * KK + k0 + fc4 * 4];
      half4_t bh;
      bh[0] = (_Float16)fmaf((float)qv.x, sc, nzs);
      bh[1] = (_Float16)fmaf((float)qv.y, sc, nzs);
      bh[2] = (_Float16)fmaf((float)qv.z, sc, nzs);
      bh[3] = (_Float16)fmaf((float)qv.w, sc, nzs);
      *(half4_t*)&sB[dst] = bh;
    }
    __syncthreads();
#pragma unroll
    for (int ks = 0; ks < 2; ++ks) {
      half8_t a[4], bfr[4];
#pragma unroll
      for (int tt = 0; tt < 4; ++tt) {
        const int rA = wr * 64 + tt * 16 + lr;
        const int j = ks * 4 + quad;
        a[tt] = *(const half8_t*)&sA[rA * 64 + ((j ^ (lr & 7)) * 8)];
        const int rB = wc * 64 + tt * 16 + lr;
        bfr[tt] = *(const half8_t*)&sB[rB * 64 + ((j ^ (lr & 7)) * 8)];
      }
#pragma unroll
      for (int mi = 0; mi < 4; ++mi)
#pragma unroll
        for (int ni = 0; ni < 4; ++ni)
          acc[mi][ni] = __builtin_amdgcn_mfma_f32_16x16x32_f16(a[mi], bfr[ni], acc[mi][ni], 0, 0, 0);
    }
    __syncthreads();
  }
#pragma unroll
  for (int ni = 0; ni < 4; ++ni) {
    const int n = n0 + wc * 64 + ni * 16 + lr;
    const float bv = bias[n];
#pragma unroll
    for (int mi = 0; mi < 4; ++mi) {
      const int mbase = m0 + wr * 64 + mi * 16 + quad * 4;
#pragma unroll
      for (int r = 0; r < 4; ++r)
        out[(size_t)(mbase + r) * NN + n] = acc[mi][ni][r] + bv;
    }
  }
}

extern "C" void kernel_launch(void* const* d_in, const int* in_sizes, int n_in,
                              void* d_out, int out_size, void* d_ws, size_t ws_size,
                              hipStream_t stream) {
  (void)in_sizes; (void)n_in; (void)out_size;
  const float* A      = (const float*)d_in[0];
  const int*   qw     = (const int*)d_in[1];
  const float* scales = (const float*)d_in[2];
  const float* zeros  = (const float*)d_in[3];
  const float* bias   = (const float*)d_in[4];
  float* out = (float*)d_out;

  const size_t needA = (size_t)MM * KK * sizeof(_Float16);  // 16 MB
  const size_t needW = (size_t)NN * KK * sizeof(_Float16);  // 32 MB

  if (ws_size >= needA + needW) {
    _Float16* Ah = (_Float16*)d_ws;
    _Float16* Wh = (_Float16*)((char*)d_ws + needA);
    prep_kernel<<<((MM + NN) * KK / 4) / 256, 256, 0, stream>>>(A, qw, scales, zeros, Ah, Wh);
    gemm_pipe<<<dim3(NN / BN * MM / BM), dim3(512), 0, stream>>>(Ah, Wh, bias, out);
  } else {
    gemm_fused<<<dim3(NN / BN * MM / BM), dim3(256), 0, stream>>>(A, qw, scales, zeros, bias, out);
  }
}